// Round 11
// baseline (250.657 us; speedup 1.0000x reference)
//
#include <hip/hip_runtime.h>
#include <math.h>

#define HIDDEN 768
#define NH 12
#define DH 64
#define SEQ 2048
#define BATCH 4

typedef __bf16 bf16;
typedef bf16 bf16x4 __attribute__((ext_vector_type(4)));
typedef bf16 bf16x8 __attribute__((ext_vector_type(8)));
typedef float f32x4 __attribute__((ext_vector_type(4)));

// global_load_lds dwordx4: per-lane global src, wave-uniform LDS base,
// HW writes lane i at base + i*16.
__device__ __forceinline__ void load_lds16(const void* g, void* l) {
    __builtin_amdgcn_global_load_lds(
        (__attribute__((address_space(1))) void*)g,
        (__attribute__((address_space(3))) void*)l, 16, 0, 0);
}

// ---------------------------------------------------------------------------
// prep_xw — fused prep_x + prep_w (R9).
// Blocks [0,3072): X fp32 -> Xb bf16. Blocks [3072,3648): weight transpose.
// ---------------------------------------------------------------------------
__global__ __launch_bounds__(256) void prep_xw(
    const float* __restrict__ X, bf16* __restrict__ Xb,
    const float* __restrict__ Wq, const float* __restrict__ Wk,
    const float* __restrict__ Wv, const float* __restrict__ Wo,
    bf16* __restrict__ Wt, bf16* __restrict__ Wot_hi,
    bf16* __restrict__ Wot_lo) {
    const int bid = blockIdx.x;
    const int tid = threadIdx.x;

    if (bid < 3072) {  // prep_x path
        const size_t i = ((size_t)bid * 256 + tid) * 8;
        float4 a = *(const float4*)(X + i);
        float4 b = *(const float4*)(X + i + 4);
        bf16x8 o = {(bf16)a.x, (bf16)a.y, (bf16)a.z, (bf16)a.w,
                    (bf16)b.x, (bf16)b.y, (bf16)b.z, (bf16)b.w};
        *(bf16x8*)(Xb + i) = o;
        return;
    }

    // prep_w path (block-uniform branch; barrier below is safe)
    __shared__ float Ts[64][68];
    const int r = bid - 3072;  // 0..575
    const int z = r / 144;
    const int rem = r - z * 144;
    const int n0 = (rem % 12) * 64, k0 = (rem / 12) * 64;
    const float* W = (z == 0) ? Wq : (z == 1) ? Wk : (z == 2) ? Wv : Wo;

    {
        const int rr = tid >> 2, c = (tid & 3) << 4;
        const float* src = W + (size_t)(k0 + rr) * HIDDEN + n0 + c;
#pragma unroll
        for (int j = 0; j < 4; ++j)
            *(float4*)&Ts[rr][c + 4 * j] = *(const float4*)(src + 4 * j);
    }
    __syncthreads();

    const int nl = tid >> 2, kc = (tid & 3) << 4;
    float v[16];
#pragma unroll
    for (int j = 0; j < 16; ++j) v[j] = Ts[kc + j][nl];

    if (z < 3) {
        bf16 hi[16];
#pragma unroll
        for (int j = 0; j < 16; ++j) hi[j] = (bf16)v[j];
        const size_t off = (size_t)(z * HIDDEN + n0 + nl) * HIDDEN + k0 + kc;
        *(bf16x8*)(Wt + off) = *(bf16x8*)&hi[0];
        *(bf16x8*)(Wt + off + 8) = *(bf16x8*)&hi[8];
    } else {
        bf16 hi[16], lo[16];
#pragma unroll
        for (int j = 0; j < 16; ++j) {
            hi[j] = (bf16)v[j];
            lo[j] = (bf16)(v[j] - (float)hi[j]);
        }
        const size_t off = (size_t)(n0 + nl) * HIDDEN + k0 + kc;
        *(bf16x8*)(Wot_hi + off) = *(bf16x8*)&hi[0];
        *(bf16x8*)(Wot_hi + off + 8) = *(bf16x8*)&hi[8];
        *(bf16x8*)(Wot_lo + off) = *(bf16x8*)&lo[0];
        *(bf16x8*)(Wot_lo + off + 8) = *(bf16x8*)&lo[8];
    }
}

// ---------------------------------------------------------------------------
// QKV GEMM — R10 structure (verified): 128m x 192n tile, T3-min 2-phase
// double buffer at BK=32, one barrier per K-step, STAGE(next) before
// COMPUTE(cur). 64B-row involution chunk16 ^= (row>>1)&3 both sides.
// XCD swizzle (R9). MFMA 16x16x32 layouts (HW-verified R1-R4).
// Q pre-scaled by 0.125*log2e.
// ---------------------------------------------------------------------------
__global__ __launch_bounds__(256, 3) void gemm_qkv(
    const bf16* __restrict__ Xb, const bf16* __restrict__ Wt,
    const float* __restrict__ bq, const float* __restrict__ bk,
    const float* __restrict__ bv, bf16* __restrict__ q_out,
    bf16* __restrict__ k_out, bf16* __restrict__ v_out) {
    __shared__ bf16 As[2][128 * 32];  // 8 KB each
    __shared__ bf16 Bs[2][192 * 32];  // 12 KB each

    const int tid = threadIdx.x;
    const int ln = tid & 63, wv = tid >> 6;
    const int quad = ln >> 4, l16 = ln & 15;
    const int wm = wv >> 1, wn = wv & 1;

    // XCD swizzle (bijective, 768%8==0)
    const int wg = blockIdx.x;
    const int xcd = wg & 7, i6 = wg >> 3;  // i6 in 0..95
    const int n0 = (i6 % 12) * 192;
    const int m0 = (xcd * 8 + i6 / 12) * 128;

    f32x4 acc[4][6];
#pragma unroll
    for (int i = 0; i < 4; ++i)
#pragma unroll
        for (int j = 0; j < 6; ++j) acc[i][j] = (f32x4){0.f, 0.f, 0.f, 0.f};

    const int srow = ln >> 2;
    const int bcol_sw = ((ln & 3) << 4) ^ (((ln >> 3) & 3) << 4);
    const char* gA =
        (const char*)Xb + ((size_t)(m0 + wv * 32 + srow) * HIDDEN) * 2 + bcol_sw;
    const char* gB =
        (const char*)Wt + ((size_t)(n0 + wv * 48 + srow) * HIDDEN) * 2 + bcol_sw;

    const int fsw = ((l16 >> 1) & 3) << 4;  // fragment byte-swizzle

    auto STAGE = [&](int b, int k0) {
#pragma unroll
        for (int j = 0; j < 2; ++j)  // A: wave rows [wv*32,+32)
            load_lds16(gA + (size_t)k0 * 2 + (size_t)j * (16 * HIDDEN * 2),
                       &As[b][(wv * 32 + j * 16) * 32]);
#pragma unroll
        for (int j = 0; j < 3; ++j)  // B: wave rows [wv*48,+48)
            load_lds16(gB + (size_t)k0 * 2 + (size_t)j * (16 * HIDDEN * 2),
                       &Bs[b][(wv * 48 + j * 16) * 32]);
    };

    auto COMPUTE = [&](int b) {
        bf16x8 ah[4], bh[6];
#pragma unroll
        for (int i = 0; i < 4; ++i)
            ah[i] = *(const bf16x8*)((const char*)&As[b][0] +
                                     (wm * 64 + i * 16 + l16) * 64 +
                                     ((quad * 16) ^ fsw));
#pragma unroll
        for (int i = 0; i < 6; ++i)
            bh[i] = *(const bf16x8*)((const char*)&Bs[b][0] +
                                     (wn * 96 + i * 16 + l16) * 64 +
                                     ((quad * 16) ^ fsw));
#pragma unroll
        for (int mi = 0; mi < 4; ++mi)
#pragma unroll
            for (int ni = 0; ni < 6; ++ni)
                acc[mi][ni] = __builtin_amdgcn_mfma_f32_16x16x32_bf16(
                    ah[mi], bh[ni], acc[mi][ni], 0, 0, 0);
    };

    STAGE(0, 0);
    __syncthreads();

    for (int step = 0; step < 24; step += 2) {
        if (step + 1 < 24) STAGE(1, (step + 1) * 32);
        COMPUTE(0);
        __syncthreads();
        if (step + 2 < 24) STAGE(0, (step + 2) * 32);
        COMPUTE(1);
        __syncthreads();
    }

    const int nb = n0 + wn * 96;           // wave's first output column
    const int which = nb / HIDDEN;         // 0=Q, 1=K, 2=V (wave-uniform)
    const int nrel = nb - which * HIDDEN;  // multiple of 96

    if (which < 2) {
        // 0.125 * log2(e) = 0.18033688011112042  (exp2-based softmax)
        const float scale = (which == 0) ? 0.18033688011112042f : 1.0f;
        const float* bias = (which == 0) ? bq : bk;
        bf16* dst = (which == 0) ? q_out : k_out;
#pragma unroll
        for (int ni = 0; ni < 6; ++ni) {
            const int nn = nrel + ni * 16;  // 16-col chunk, within one head
            const int h = nn >> 6;
            const int dh = (nn & 63) + l16;
            const float bb = bias[nn + l16];
#pragma unroll
            for (int mi = 0; mi < 4; ++mi)
#pragma unroll
                for (int r = 0; r < 4; ++r) {
                    const int m = m0 + wm * 64 + mi * 16 + quad * 4 + r;
                    const int bi = m >> 11, s = m & (SEQ - 1);
                    dst[(((size_t)(bi * NH + h) * SEQ + s) << 6) + dh] =
                        (bf16)(scale * (acc[mi][ni][r] + bb));
                }
        }
    } else {
        // V transposed: Vt[b][h][d][s]
        const int bi = m0 >> 11;
        const int sbase = (m0 & (SEQ - 1)) + wm * 64;
#pragma unroll
        for (int ni = 0; ni < 6; ++ni) {
            const int nn = nrel + ni * 16;
            const int h = nn >> 6;
            const int dh = (nn & 63) + l16;
            const float bb = bv[nn + l16];
            bf16* vrow = v_out + ((size_t)(bi * NH + h) * DH + dh) * SEQ;
#pragma unroll
            for (int mi = 0; mi < 4; ++mi) {
                bf16x4 pk = {(bf16)(acc[mi][ni][0] + bb),
                             (bf16)(acc[mi][ni][1] + bb),
                             (bf16)(acc[mi][ni][2] + bb),
                             (bf16)(acc[mi][ni][3] + bb)};
                *(bf16x4*)(vrow + sbase + mi * 16 + quad * 4) = pk;
            }
        }
    }
}

// ---------------------------------------------------------------------------
// MFMA flash attention — ROUND-11: KVBLK 64 -> 128 with the SAME sync
// structure (2 barriers per staged tile). Barrier pairs 32 -> 16; each
// iteration computes two 64-key sub-phases whose math is byte-identical to
// the R4 loop body (same key order -> bit-identical l_i and output).
// Register-prefetch distance doubles (loads for tile kt2+1 issued one full
// 2-sub-phase iteration early). Per-key staging instruction count unchanged.
//
// LDS budget for 3 blocks/CU: Ks[128][64] 16K + Vts[64][128] 16K +
// Ps[128][64] 16K + mask cache 4K = 52.1K (x3 = 156K <= 160K). Mask cached
// as BF16 (0/1 exactly representable; on the fastmask path it is only read
// in the prologue; !fastmask ext values 0/1 convert exactly).
//
// Swizzle (R2-verified involution, re-audited): col ^= ((row&7)<<3). All
// added offsets (ks*64 cols in Vts, +64 rows in Ks, kt2 strides) are
// multiples of 8 / outside the XOR bits -> bank patterns unchanged.
// XCD swizzle (R4): FETCH 104->18.5MB. No setprio (R3/m190).
// ---------------------------------------------------------------------------
__global__ __launch_bounds__(256) void attn_mfma(const bf16* __restrict__ Q,
                                                 const bf16* __restrict__ K,
                                                 const bf16* __restrict__ Vt,
                                                 const float* __restrict__ mask,
                                                 bf16* __restrict__ ctx_hi,
                                                 bf16* __restrict__ ctx_lo) {
    __shared__ bf16 Ks[128 * 64];   // [key][d], swz col^((key&7)<<3)
    __shared__ bf16 Vts[64 * 128];  // [d][key], swz col^((d&7)<<3)
    __shared__ bf16 Ps[128 * 64];
    __shared__ bf16 Msb[SEQ];       // mask row as bf16 (0/1 exact)
    __shared__ int allones_s;

    const int tid = threadIdx.x;
    const int ln = tid & 63, w = tid >> 6;
    const int quad = ln >> 4, l16 = ln & 15;

    // XCD-aware swizzle: wg%8 = XCD; give each XCD a contiguous logical range.
    const int wg = blockIdx.x;                      // 0..767
    const int logical = (wg & 7) * 96 + (wg >> 3);  // bijective (768%8==0)
    const int qt = logical & 15;
    const int h = (logical >> 4) % NH;
    const int b = logical / (16 * NH);

    const size_t bh = (size_t)b * NH + h;
    const bf16* Qp = Q + ((bh * SEQ + (size_t)qt * 128) << 6);
    const bf16* Kp = K + (bh * SEQ << 6);
    const bf16* Vp = Vt + (bh * DH) * SEQ;

    // cache mask row (bf16), compute block-uniform all-ones flag
    if (tid == 0) allones_s = 1;
    {
        float4 m0 = *(const float4*)(mask + (size_t)b * SEQ + tid * 8);
        float4 m1 = *(const float4*)(mask + (size_t)b * SEQ + tid * 8 + 4);
        bf16x8 mb = {(bf16)m0.x, (bf16)m0.y, (bf16)m0.z, (bf16)m0.w,
                     (bf16)m1.x, (bf16)m1.y, (bf16)m1.z, (bf16)m1.w};
        *(bf16x8*)&Msb[tid * 8] = mb;
        bool ok = (m0.x == 1.f) & (m0.y == 1.f) & (m0.z == 1.f) &
                  (m0.w == 1.f) & (m1.x == 1.f) & (m1.y == 1.f) &
                  (m1.z == 1.f) & (m1.w == 1.f);
        __syncthreads();
        if (!ok) allones_s = 0;  // benign race: all writers store 0
    }
    __syncthreads();
    const bool fastmask = (allones_s != 0);

    // Q frags (B-operand of S^T)
    bf16x8 qb[2][2];
#pragma unroll
    for (int qg = 0; qg < 2; ++qg)
#pragma unroll
        for (int hf = 0; hf < 2; ++hf)
            qb[qg][hf] = *(const bf16x8*)(Qp + ((w * 32 + qg * 16 + l16) << 6) +
                                          hf * 32 + quad * 8);
    float mq[2];
#pragma unroll
    for (int qg = 0; qg < 2; ++qg)
        mq[qg] = (float)Msb[qt * 128 + w * 32 + qg * 16 + l16];

    float l_i[2] = {0.f, 0.f};  // lane-partial row sums (over this quad's keys)
    f32x4 acc[4][2];
#pragma unroll
    for (int fd = 0; fd < 4; ++fd)
#pragma unroll
        for (int qg = 0; qg < 2; ++qg) acc[fd][qg] = (f32x4){0.f, 0.f, 0.f, 0.f};

    // staging: thread covers K rows {sr, sr+64} and V (row sr=dh) key cols
    // {sc, sc+8, sc+64, sc+72} per 128-key tile. swz col ^= ((row&7)<<3).
    const int sr = tid >> 2, sc = (tid & 3) << 4;
    const int ssw = (sr & 7) << 3;
    const int d0 = sc ^ ssw, d1 = (sc + 8) ^ ssw;
    const bf16* kbase = Kp + ((size_t)sr << 6) + sc;   // key row sr
    const bf16* vbase = Vp + (size_t)sr * SEQ + sc;    // d row sr, key col sc

    const int NT2 = SEQ / 128;  // 16 staged tiles
    bf16x8 kr0, kr1, kr2, kr3, vr0, vr1, vr2, vr3;
    kr0 = *(const bf16x8*)kbase;
    kr1 = *(const bf16x8*)(kbase + 8);
    kr2 = *(const bf16x8*)(kbase + 4096);      // key row sr+64
    kr3 = *(const bf16x8*)(kbase + 4096 + 8);
    vr0 = *(const bf16x8*)vbase;
    vr1 = *(const bf16x8*)(vbase + 8);
    vr2 = *(const bf16x8*)(vbase + 64);
    vr3 = *(const bf16x8*)(vbase + 72);

    const int fsw = (l16 & 7) << 3;  // fragment swizzle (row&7 == l16&7)

    for (int kt2 = 0; kt2 < NT2; ++kt2) {
        __syncthreads();  // readers of tile kt2-1 done
        *(bf16x8*)&Ks[sr * 64 + d0] = kr0;
        *(bf16x8*)&Ks[sr * 64 + d1] = kr1;
        *(bf16x8*)&Ks[(sr + 64) * 64 + d0] = kr2;   // (sr+64)&7 == sr&7
        *(bf16x8*)&Ks[(sr + 64) * 64 + d1] = kr3;
        *(bf16x8*)&Vts[sr * 128 + d0] = vr0;
        *(bf16x8*)&Vts[sr * 128 + d1] = vr1;
        *(bf16x8*)&Vts[sr * 128 + d0 + 64] = vr2;   // bit6 outside XOR
        *(bf16x8*)&Vts[sr * 128 + d1 + 64] = vr3;
        __syncthreads();
        if (kt2 + 1 < NT2) {
            const size_t ko = (size_t)(kt2 + 1) << 13;  // 128 rows * 64
            kr0 = *(const bf16x8*)(kbase + ko);
            kr1 = *(const bf16x8*)(kbase + ko + 8);
            kr2 = *(const bf16x8*)(kbase + ko + 4096);
            kr3 = *(const bf16x8*)(kbase + ko + 4096 + 8);
            const int vo = (kt2 + 1) * 128;
            vr0 = *(const bf16x8*)(vbase + vo);
            vr1 = *(const bf16x8*)(vbase + vo + 8);
            vr2 = *(const bf16x8*)(vbase + vo + 64);
            vr3 = *(const bf16x8*)(vbase + vo + 72);
        }

#pragma unroll
        for (int ks = 0; ks < 2; ++ks) {  // two 64-key sub-phases
            // S^T = K.Q^T
            f32x4 st[4][2];
#pragma unroll
            for (int f = 0; f < 4; ++f) {
                const int krow = (ks * 64 + f * 16 + l16) * 64;
                bf16x8 ka0 = *(bf16x8*)&Ks[krow + ((quad * 8) ^ fsw)];
                bf16x8 ka1 = *(bf16x8*)&Ks[krow + ((32 + quad * 8) ^ fsw)];
#pragma unroll
                for (int qg = 0; qg < 2; ++qg) {
                    f32x4 c = {0.f, 0.f, 0.f, 0.f};
                    c = __builtin_amdgcn_mfma_f32_16x16x32_bf16(ka0, qb[qg][0], c, 0, 0, 0);
                    c = __builtin_amdgcn_mfma_f32_16x16x32_bf16(ka1, qb[qg][1], c, 0, 0, 0);
                    st[f][qg] = c;
                }
            }

            if (!fastmask) {
#pragma unroll
                for (int f = 0; f < 4; ++f) {
                    const bf16x4 mk4 = *(const bf16x4*)&Msb[kt2 * 128 + ks * 64 +
                                                            f * 16 + quad * 4];
                    const float mkk[4] = {(float)mk4[0], (float)mk4[1],
                                          (float)mk4[2], (float)mk4[3]};
#pragma unroll
                    for (int qg = 0; qg < 2; ++qg)
#pragma unroll
                        for (int r = 0; r < 4; ++r) {
                            const float ext = mq[qg] * mkk[r];
                            // st is in log2 domain: 1e9*log2e = 1.4427e9
                            st[f][qg][r] =
                                ext * st[f][qg][r] - (1.0f - ext) * 1.4426950e9f;
                        }
                }
            }

            // exp2 (no shift), lane-partial sums, pack P into swizzled Ps
#pragma unroll
            for (int qg = 0; qg < 2; ++qg) {
                const int row = w * 32 + qg * 16 + l16;
                const int sw = (row & 7) << 3;
                bf16* prow = &Ps[row * 64];
#pragma unroll
                for (int f = 0; f < 4; ++f) {
                    float p0 = __builtin_amdgcn_exp2f(st[f][qg][0]);
                    float p1 = __builtin_amdgcn_exp2f(st[f][qg][1]);
                    float p2 = __builtin_amdgcn_exp2f(st[f][qg][2]);
                    float p3 = __builtin_amdgcn_exp2f(st[f][qg][3]);
                    l_i[qg] += (p0 + p1) + (p2 + p3);
                    bf16x4 pk = {(bf16)p0, (bf16)p1, (bf16)p2, (bf16)p3};
                    *(bf16x4*)&prow[(f * 16 + quad * 4) ^ sw] = pk;
                }
            }

            // O^T += V^T.P^T (Ps rows wave-local: no barrier)
            bf16x8 pb[2][2];
#pragma unroll
            for (int qg = 0; qg < 2; ++qg) {
                const int row = w * 32 + qg * 16 + l16;
                const int sw = (row & 7) << 3;
#pragma unroll
                for (int hf = 0; hf < 2; ++hf)
                    pb[qg][hf] =
                        *(bf16x8*)&Ps[row * 64 + ((hf * 32 + quad * 8) ^ sw)];
            }
#pragma unroll
            for (int fd = 0; fd < 4; ++fd) {
                const int vrow = (fd * 16 + l16) * 128 + ks * 64;
                bf16x8 va0 = *(bf16x8*)&Vts[vrow + ((quad * 8) ^ fsw)];
                bf16x8 va1 = *(bf16x8*)&Vts[vrow + ((32 + quad * 8) ^ fsw)];
#pragma unroll
                for (int qg = 0; qg < 2; ++qg) {
                    f32x4 c = acc[fd][qg];
                    c = __builtin_amdgcn_mfma_f32_16x16x32_bf16(va0, pb[qg][0], c, 0, 0, 0);
                    c = __builtin_amdgcn_mfma_f32_16x16x32_bf16(va1, pb[qg][1], c, 0, 0, 0);
                    acc[fd][qg] = c;
                }
            }
        }
    }

    // final row-sum reduction across quads (query id = l16 only)
#pragma unroll
    for (int qg = 0; qg < 2; ++qg) {
        l_i[qg] += __shfl_xor(l_i[qg], 16);
        l_i[qg] += __shfl_xor(l_i[qg], 32);
    }

    // epilogue: ctx pre-split bf16 hi/lo [B*S][768] (split done ONCE here)
#pragma unroll
    for (int qg = 0; qg < 2; ++qg) {
        const float inv = 1.0f / l_i[qg];
        const size_t row = (size_t)b * SEQ + qt * 128 + w * 32 + qg * 16 + l16;
#pragma unroll
        for (int fd = 0; fd < 4; ++fd) {
            bf16 hi[4], lo[4];
#pragma unroll
            for (int r = 0; r < 4; ++r) {
                const float o = acc[fd][qg][r] * inv;
                hi[r] = (bf16)o;
                lo[r] = (bf16)(o - (float)hi[r]);
            }
            const size_t off = row * HIDDEN + h * 64 + fd * 16 + quad * 4;
            *(bf16x4*)(ctx_hi + off) = *(bf16x4*)&hi[0];
            *(bf16x4*)(ctx_lo + off) = *(bf16x4*)&lo[0];
        }
    }
}

// ---------------------------------------------------------------------------
// Output GEMM — R10 structure (verified): T3-min 2-phase dbuf at BK=32,
// one barrier per K-step, STAGE before COMPUTE. 64B-row involution both
// sides; XCD swizzle (R9). 3-term: ah*bh + ah*bl + al*bh.
// ---------------------------------------------------------------------------
__global__ __launch_bounds__(256) void gemm_out(const bf16* __restrict__ Ah,
                                                const bf16* __restrict__ Al,
                                                const bf16* __restrict__ Bhi,
                                                const bf16* __restrict__ Blo,
                                                const float* __restrict__ bo,
                                                float* __restrict__ fout) {
    __shared__ bf16 Ash[2][128 * 32];
    __shared__ bf16 Asl[2][128 * 32];
    __shared__ bf16 Bsh[2][64 * 32];
    __shared__ bf16 Bsl[2][64 * 32];

    const int tid = threadIdx.x;
    const int ln = tid & 63, wv = tid >> 6;
    const int quad = ln >> 4, l16 = ln & 15;
    const int wm = wv >> 1, wn = wv & 1;

    // XCD swizzle (bijective, 768%8==0)
    const int wg = blockIdx.x;
    const int xcd = wg & 7, i6 = wg >> 3;  // i6 in 0..95
    const int n0 = (i6 % 12) * 64;
    const int m0 = (xcd * 8 + i6 / 12) * 128;

    f32x4 acc[4][2];
#pragma unroll
    for (int i = 0; i < 4; ++i)
#pragma unroll
        for (int j = 0; j < 2; ++j) acc[i][j] = (f32x4){0.f, 0.f, 0.f, 0.f};

    const int srow = ln >> 2;
    const int bcol_sw = ((ln & 3) << 4) ^ (((ln >> 3) & 3) << 4);
    const char* gAh =
        (const char*)Ah + ((size_t)(m0 + wv * 32 + srow) * HIDDEN) * 2 + bcol_sw;
    const char* gAl =
        (const char*)Al + ((size_t)(m0 + wv * 32 + srow) * HIDDEN) * 2 + bcol_sw;
    const char* gBh =
        (const char*)Bhi + ((size_t)(n0 + wv * 16 + srow) * HIDDEN) * 2 + bcol_sw;
    const char* gBl =
        (const char*)Blo + ((size_t)(n0 + wv * 16 + srow) * HIDDEN) * 2 + bcol_sw;

    const int fsw = ((l16 >> 1) & 3) << 4;  // fragment byte-swizzle

    auto STAGE = [&](int b, int k0) {
#pragma unroll
        for (int j = 0; j < 2; ++j) {  // A hi/lo: wave rows [wv*32,+32)
            load_lds16(gAh + (size_t)k0 * 2 + (size_t)j * (16 * HIDDEN * 2),
                       &Ash[b][(wv * 32 + j * 16) * 32]);
            load_lds16(gAl + (size_t)k0 * 2 + (size_t)j * (16 * HIDDEN * 2),
                       &Asl[b][(wv * 32 + j * 16) * 32]);
        }
        // B hi/lo: wave rows [wv*16,+16)
        load_lds16(gBh + (size_t)k0 * 2, &Bsh[b][(wv * 16) * 32]);
        load_lds16(gBl + (size_t)k0 * 2, &Bsl[b][(wv * 16) * 32]);
    };

    auto COMPUTE = [&](int b) {
        bf16x8 ah[4], al[4], bh[2], bl[2];
#pragma unroll
        for (int i = 0; i < 4; ++i) {
            const int row = (wm * 64 + i * 16 + l16) * 64;
            ah[i] = *(const bf16x8*)((const char*)&Ash[b][0] + row +
                                     ((quad * 16) ^ fsw));
            al[i] = *(const bf16x8*)((const char*)&Asl[b][0] + row +
                                     ((quad * 16) ^ fsw));
        }
#pragma unroll
        for (int i = 0; i < 2; ++i) {
            const int row = (wn * 32 + i * 16 + l16) * 64;
            bh[i] = *(const bf16x8*)((const char*)&Bsh[b][0] + row +
                                     ((quad * 16) ^ fsw));
            bl[i] = *(const bf16x8*)((const char*)&Bsl[b][0] + row +
                                     ((quad * 16) ^ fsw));
        }
#pragma unroll
        for (int mi = 0; mi < 4; ++mi)
#pragma unroll
            for (int ni = 0; ni < 2; ++ni) {
                f32x4 c = acc[mi][ni];
                c = __builtin_amdgcn_mfma_f32_16x16x32_bf16(ah[mi], bh[ni], c, 0, 0, 0);
                c = __builtin_amdgcn_mfma_f32_16x16x32_bf16(ah[mi], bl[ni], c, 0, 0, 0);
                c = __builtin_amdgcn_mfma_f32_16x16x32_bf16(al[mi], bh[ni], c, 0, 0, 0);
                acc[mi][ni] = c;
            }
    };

    STAGE(0, 0);
    __syncthreads();

    for (int step = 0; step < 24; step += 2) {
        if (step + 1 < 24) STAGE(1, (step + 1) * 32);
        COMPUTE(0);
        __syncthreads();
        if (step + 2 < 24) STAGE(0, (step + 2) * 32);
        COMPUTE(1);
        __syncthreads();
    }

#pragma unroll
    for (int ni = 0; ni < 2; ++ni) {
        const int n = n0 + wn * 32 + ni * 16 + l16;
        const float bb = bo[n];
#pragma unroll
        for (int mi = 0; mi < 4; ++mi)
#pragma unroll
            for (int r = 0; r < 4; ++r) {
                const int m = m0 + wm * 64 + mi * 16 + quad * 4 + r;
                float x = acc[mi][ni][r] + bb;
                x = 0.5f * x * (1.0f + erff(x * 0.70710678118654752440f));
                fout[(size_t)m * HIDDEN + n] = x;
            }
    }
}

// ---------------------------------------------------------------------------
extern "C" void kernel_launch(void* const* d_in, const int* in_sizes, int n_in,
                              void* d_out, int out_size, void* d_ws, size_t ws_size,
                              hipStream_t stream) {
    const float* X    = (const float*)d_in[0];
    const float* mask = (const float*)d_in[1];
    const float* Wq   = (const float*)d_in[2];
    const float* bq   = (const float*)d_in[3];
    const float* Wk   = (const float*)d_in[4];
    const float* bk   = (const float*)d_in[5];
    const float* Wv   = (const float*)d_in[6];
    const float* bv   = (const float*)d_in[7];
    const float* Wo   = (const float*)d_in[8];
    const float* bo   = (const float*)d_in[9];
    float* out = (float*)d_out;

    char* w = (char*)d_ws;
    const size_t NE = (size_t)BATCH * SEQ * HIDDEN;  // 6.29M elems
    bf16* q_ws   = (bf16*)w;  w += NE * 2;
    bf16* k_ws   = (bf16*)w;  w += NE * 2;
    bf16* vt_ws  = (bf16*)w;  w += NE * 2;
    bf16* ctx_hi = (bf16*)w;  w += NE * 2;
    bf16* ctx_lo = (bf16*)w;  w += NE * 2;
    bf16* Xb     = (bf16*)w;  w += NE * 2;
    bf16* Wt     = (bf16*)w;  w += (size_t)3 * HIDDEN * HIDDEN * 2;
    bf16* Wot_hi = (bf16*)w;  w += (size_t)HIDDEN * HIDDEN * 2;
    bf16* Wot_lo = (bf16*)w;  w += (size_t)HIDDEN * HIDDEN * 2;

    prep_xw<<<3648, 256, 0, stream>>>(X, Xb, Wq, Wk, Wv, Wo, Wt, Wot_hi,
                                      Wot_lo);
    gemm_qkv<<<dim3(768), 256, 0, stream>>>(Xb, Wt, bq, bk, bv, q_ws, k_ws,
                                            vt_ws);
    attn_mfma<<<dim3(16 * NH * BATCH), 256, 0, stream>>>(
        q_ws, k_ws, vt_ws, mask, ctx_hi, ctx_lo);
    gemm_out<<<dim3(768), 256, 0, stream>>>(ctx_hi, ctx_lo, Wot_hi, Wot_lo,
                                            bo, out);
}

// Round 12
// 246.909 us; speedup vs baseline: 1.0152x; 1.0152x over previous
//
#include <hip/hip_runtime.h>
#include <math.h>

#define HIDDEN 768
#define NH 12
#define DH 64
#define SEQ 2048
#define BATCH 4

typedef __bf16 bf16;
typedef bf16 bf16x4 __attribute__((ext_vector_type(4)));
typedef bf16 bf16x8 __attribute__((ext_vector_type(8)));
typedef float f32x4 __attribute__((ext_vector_type(4)));

// global_load_lds dwordx4: per-lane global src, wave-uniform LDS base,
// HW writes lane i at base + i*16.
__device__ __forceinline__ void load_lds16(const void* g, void* l) {
    __builtin_amdgcn_global_load_lds(
        (__attribute__((address_space(1))) void*)g,
        (__attribute__((address_space(3))) void*)l, 16, 0, 0);
}

// ---------------------------------------------------------------------------
// prep_xw — fused prep_x + prep_w (R9).
// Blocks [0,3072): X fp32 -> Xb bf16. Blocks [3072,3648): weight transpose.
// ---------------------------------------------------------------------------
__global__ __launch_bounds__(256) void prep_xw(
    const float* __restrict__ X, bf16* __restrict__ Xb,
    const float* __restrict__ Wq, const float* __restrict__ Wk,
    const float* __restrict__ Wv, const float* __restrict__ Wo,
    bf16* __restrict__ Wt, bf16* __restrict__ Wot_hi,
    bf16* __restrict__ Wot_lo) {
    const int bid = blockIdx.x;
    const int tid = threadIdx.x;

    if (bid < 3072) {  // prep_x path
        const size_t i = ((size_t)bid * 256 + tid) * 8;
        float4 a = *(const float4*)(X + i);
        float4 b = *(const float4*)(X + i + 4);
        bf16x8 o = {(bf16)a.x, (bf16)a.y, (bf16)a.z, (bf16)a.w,
                    (bf16)b.x, (bf16)b.y, (bf16)b.z, (bf16)b.w};
        *(bf16x8*)(Xb + i) = o;
        return;
    }

    // prep_w path (block-uniform branch; barrier below is safe)
    __shared__ float Ts[64][68];
    const int r = bid - 3072;  // 0..575
    const int z = r / 144;
    const int rem = r - z * 144;
    const int n0 = (rem % 12) * 64, k0 = (rem / 12) * 64;
    const float* W = (z == 0) ? Wq : (z == 1) ? Wk : (z == 2) ? Wv : Wo;

    {
        const int rr = tid >> 2, c = (tid & 3) << 4;
        const float* src = W + (size_t)(k0 + rr) * HIDDEN + n0 + c;
#pragma unroll
        for (int j = 0; j < 4; ++j)
            *(float4*)&Ts[rr][c + 4 * j] = *(const float4*)(src + 4 * j);
    }
    __syncthreads();

    const int nl = tid >> 2, kc = (tid & 3) << 4;
    float v[16];
#pragma unroll
    for (int j = 0; j < 16; ++j) v[j] = Ts[kc + j][nl];

    if (z < 3) {
        bf16 hi[16];
#pragma unroll
        for (int j = 0; j < 16; ++j) hi[j] = (bf16)v[j];
        const size_t off = (size_t)(z * HIDDEN + n0 + nl) * HIDDEN + k0 + kc;
        *(bf16x8*)(Wt + off) = *(bf16x8*)&hi[0];
        *(bf16x8*)(Wt + off + 8) = *(bf16x8*)&hi[8];
    } else {
        bf16 hi[16], lo[16];
#pragma unroll
        for (int j = 0; j < 16; ++j) {
            hi[j] = (bf16)v[j];
            lo[j] = (bf16)(v[j] - (float)hi[j]);
        }
        const size_t off = (size_t)(n0 + nl) * HIDDEN + k0 + kc;
        *(bf16x8*)(Wot_hi + off) = *(bf16x8*)&hi[0];
        *(bf16x8*)(Wot_hi + off + 8) = *(bf16x8*)&hi[8];
        *(bf16x8*)(Wot_lo + off) = *(bf16x8*)&lo[0];
        *(bf16x8*)(Wot_lo + off + 8) = *(bf16x8*)&lo[8];
    }
}

// ---------------------------------------------------------------------------
// QKV GEMM — R10 structure (verified best): 128m x 192n tile, T3-min
// 2-phase double buffer at BK=32, one barrier per K-step, STAGE(next)
// before COMPUTE(cur). 64B-row involution chunk16 ^= (row>>1)&3 both sides.
// XCD swizzle (R9). MFMA 16x16x32 layouts (HW-verified R1-R4).
// Q pre-scaled by 0.125*log2e.
// ---------------------------------------------------------------------------
__global__ __launch_bounds__(256, 3) void gemm_qkv(
    const bf16* __restrict__ Xb, const bf16* __restrict__ Wt,
    const float* __restrict__ bq, const float* __restrict__ bk,
    const float* __restrict__ bv, bf16* __restrict__ q_out,
    bf16* __restrict__ k_out, bf16* __restrict__ v_out) {
    __shared__ bf16 As[2][128 * 32];  // 8 KB each
    __shared__ bf16 Bs[2][192 * 32];  // 12 KB each

    const int tid = threadIdx.x;
    const int ln = tid & 63, wv = tid >> 6;
    const int quad = ln >> 4, l16 = ln & 15;
    const int wm = wv >> 1, wn = wv & 1;

    // XCD swizzle (bijective, 768%8==0)
    const int wg = blockIdx.x;
    const int xcd = wg & 7, i6 = wg >> 3;  // i6 in 0..95
    const int n0 = (i6 % 12) * 192;
    const int m0 = (xcd * 8 + i6 / 12) * 128;

    f32x4 acc[4][6];
#pragma unroll
    for (int i = 0; i < 4; ++i)
#pragma unroll
        for (int j = 0; j < 6; ++j) acc[i][j] = (f32x4){0.f, 0.f, 0.f, 0.f};

    const int srow = ln >> 2;
    const int bcol_sw = ((ln & 3) << 4) ^ (((ln >> 3) & 3) << 4);
    const char* gA =
        (const char*)Xb + ((size_t)(m0 + wv * 32 + srow) * HIDDEN) * 2 + bcol_sw;
    const char* gB =
        (const char*)Wt + ((size_t)(n0 + wv * 48 + srow) * HIDDEN) * 2 + bcol_sw;

    const int fsw = ((l16 >> 1) & 3) << 4;  // fragment byte-swizzle

    auto STAGE = [&](int b, int k0) {
#pragma unroll
        for (int j = 0; j < 2; ++j)  // A: wave rows [wv*32,+32)
            load_lds16(gA + (size_t)k0 * 2 + (size_t)j * (16 * HIDDEN * 2),
                       &As[b][(wv * 32 + j * 16) * 32]);
#pragma unroll
        for (int j = 0; j < 3; ++j)  // B: wave rows [wv*48,+48)
            load_lds16(gB + (size_t)k0 * 2 + (size_t)j * (16 * HIDDEN * 2),
                       &Bs[b][(wv * 48 + j * 16) * 32]);
    };

    auto COMPUTE = [&](int b) {
        bf16x8 ah[4], bh[6];
#pragma unroll
        for (int i = 0; i < 4; ++i)
            ah[i] = *(const bf16x8*)((const char*)&As[b][0] +
                                     (wm * 64 + i * 16 + l16) * 64 +
                                     ((quad * 16) ^ fsw));
#pragma unroll
        for (int i = 0; i < 6; ++i)
            bh[i] = *(const bf16x8*)((const char*)&Bs[b][0] +
                                     (wn * 96 + i * 16 + l16) * 64 +
                                     ((quad * 16) ^ fsw));
#pragma unroll
        for (int mi = 0; mi < 4; ++mi)
#pragma unroll
            for (int ni = 0; ni < 6; ++ni)
                acc[mi][ni] = __builtin_amdgcn_mfma_f32_16x16x32_bf16(
                    ah[mi], bh[ni], acc[mi][ni], 0, 0, 0);
    };

    STAGE(0, 0);
    __syncthreads();

    for (int step = 0; step < 24; step += 2) {
        if (step + 1 < 24) STAGE(1, (step + 1) * 32);
        COMPUTE(0);
        __syncthreads();  // drains stage(step+1); orders reads(0) vs overwrite
        if (step + 2 < 24) STAGE(0, (step + 2) * 32);
        COMPUTE(1);
        __syncthreads();
    }

    const int nb = n0 + wn * 96;           // wave's first output column
    const int which = nb / HIDDEN;         // 0=Q, 1=K, 2=V (wave-uniform)
    const int nrel = nb - which * HIDDEN;  // multiple of 96

    if (which < 2) {
        // 0.125 * log2(e) = 0.18033688011112042  (exp2-based softmax)
        const float scale = (which == 0) ? 0.18033688011112042f : 1.0f;
        const float* bias = (which == 0) ? bq : bk;
        bf16* dst = (which == 0) ? q_out : k_out;
#pragma unroll
        for (int ni = 0; ni < 6; ++ni) {
            const int nn = nrel + ni * 16;  // 16-col chunk, within one head
            const int h = nn >> 6;
            const int dh = (nn & 63) + l16;
            const float bb = bias[nn + l16];
#pragma unroll
            for (int mi = 0; mi < 4; ++mi)
#pragma unroll
                for (int r = 0; r < 4; ++r) {
                    const int m = m0 + wm * 64 + mi * 16 + quad * 4 + r;
                    const int bi = m >> 11, s = m & (SEQ - 1);
                    dst[(((size_t)(bi * NH + h) * SEQ + s) << 6) + dh] =
                        (bf16)(scale * (acc[mi][ni][r] + bb));
                }
        }
    } else {
        // V transposed: Vt[b][h][d][s]
        const int bi = m0 >> 11;
        const int sbase = (m0 & (SEQ - 1)) + wm * 64;
#pragma unroll
        for (int ni = 0; ni < 6; ++ni) {
            const int nn = nrel + ni * 16;
            const int h = nn >> 6;
            const int dh = (nn & 63) + l16;
            const float bb = bv[nn + l16];
            bf16* vrow = v_out + ((size_t)(bi * NH + h) * DH + dh) * SEQ;
#pragma unroll
            for (int mi = 0; mi < 4; ++mi) {
                bf16x4 pk = {(bf16)(acc[mi][ni][0] + bb),
                             (bf16)(acc[mi][ni][1] + bb),
                             (bf16)(acc[mi][ni][2] + bb),
                             (bf16)(acc[mi][ni][3] + bb)};
                *(bf16x4*)(vrow + sbase + mi * 16 + quad * 4) = pk;
            }
        }
    }
}

// ---------------------------------------------------------------------------
// MFMA flash attention — R4/R6 configuration (best measured, KVBLK=64;
// R11's KVBLK=128 doubled bank conflicts via a stride-mismatched swizzle
// and regressed — reverted). Epilogue writes ctx PRE-SPLIT bf16 hi/lo (R7).
// XCD swizzle (R4): FETCH 104->18.5MB. LDS XOR swizzle (R2, verified at
// 64-elem row stride). No setprio (R3/m190), Ms in LDS (R3 lesson),
// single-buffer 2-phase staging (R5: dbuf null).
// ---------------------------------------------------------------------------
__global__ __launch_bounds__(256) void attn_mfma(const bf16* __restrict__ Q,
                                                 const bf16* __restrict__ K,
                                                 const bf16* __restrict__ Vt,
                                                 const float* __restrict__ mask,
                                                 bf16* __restrict__ ctx_hi,
                                                 bf16* __restrict__ ctx_lo) {
    __shared__ bf16 Ks[64 * 64];
    __shared__ bf16 Vts[64 * 64];
    __shared__ bf16 Ps[128 * 64];
    __shared__ float Ms[SEQ];
    __shared__ int allones_s;

    const int tid = threadIdx.x;
    const int ln = tid & 63, w = tid >> 6;
    const int quad = ln >> 4, l16 = ln & 15;

    // XCD-aware swizzle: wg%8 = XCD; give each XCD a contiguous logical range.
    const int wg = blockIdx.x;                      // 0..767
    const int logical = (wg & 7) * 96 + (wg >> 3);  // bijective (768%8==0)
    const int qt = logical & 15;
    const int h = (logical >> 4) % NH;
    const int b = logical / (16 * NH);

    const size_t bh = (size_t)b * NH + h;
    const bf16* Qp = Q + ((bh * SEQ + (size_t)qt * 128) << 6);
    const bf16* Kp = K + (bh * SEQ << 6);
    const bf16* Vp = Vt + (bh * DH) * SEQ;

    // cache mask row, compute block-uniform all-ones flag
    if (tid == 0) allones_s = 1;
    {
        float4 m0 = *(const float4*)(mask + (size_t)b * SEQ + tid * 8);
        float4 m1 = *(const float4*)(mask + (size_t)b * SEQ + tid * 8 + 4);
        *(float4*)&Ms[tid * 8] = m0;
        *(float4*)&Ms[tid * 8 + 4] = m1;
        bool ok = (m0.x == 1.f) & (m0.y == 1.f) & (m0.z == 1.f) &
                  (m0.w == 1.f) & (m1.x == 1.f) & (m1.y == 1.f) &
                  (m1.z == 1.f) & (m1.w == 1.f);
        __syncthreads();
        if (!ok) allones_s = 0;  // benign race: all writers store 0
    }
    __syncthreads();
    const bool fastmask = (allones_s != 0);

    // Q frags (B-operand of S^T)
    bf16x8 qb[2][2];
#pragma unroll
    for (int qg = 0; qg < 2; ++qg)
#pragma unroll
        for (int hf = 0; hf < 2; ++hf)
            qb[qg][hf] = *(const bf16x8*)(Qp + ((w * 32 + qg * 16 + l16) << 6) +
                                          hf * 32 + quad * 8);
    float mq[2];
#pragma unroll
    for (int qg = 0; qg < 2; ++qg)
        mq[qg] = Ms[qt * 128 + w * 32 + qg * 16 + l16];

    float l_i[2] = {0.f, 0.f};  // lane-partial row sums (over this quad's keys)
    f32x4 acc[4][2];
#pragma unroll
    for (int fd = 0; fd < 4; ++fd)
#pragma unroll
        for (int qg = 0; qg < 2; ++qg) acc[fd][qg] = (f32x4){0.f, 0.f, 0.f, 0.f};

    // staging: 64 rows x 64 cols, swizzled col = c ^ ((row&7)<<3)
    const int sr = tid >> 2, sc = (tid & 3) << 4;
    const int ssw = (sr & 7) << 3;
    const int d0 = sc ^ ssw, d1 = (sc + 8) ^ ssw;
    const bf16* kbase = Kp + ((size_t)sr << 6) + sc;
    const bf16* vbase = Vp + (size_t)sr * SEQ + sc;

    bf16x8 kr0, kr1, vr0, vr1;
    kr0 = *(const bf16x8*)kbase;
    kr1 = *(const bf16x8*)(kbase + 8);
    vr0 = *(const bf16x8*)vbase;
    vr1 = *(const bf16x8*)(vbase + 8);

    for (int kt = 0; kt < SEQ / 64; ++kt) {
        __syncthreads();  // readers of tile kt-1 done
        *(bf16x8*)&Ks[sr * 64 + d0] = kr0;
        *(bf16x8*)&Ks[sr * 64 + d1] = kr1;
        *(bf16x8*)&Vts[sr * 64 + d0] = vr0;
        *(bf16x8*)&Vts[sr * 64 + d1] = vr1;
        __syncthreads();
        if (kt + 1 < SEQ / 64) {
            kr0 = *(const bf16x8*)(kbase + ((size_t)(kt + 1) << 12));
            kr1 = *(const bf16x8*)(kbase + ((size_t)(kt + 1) << 12) + 8);
            vr0 = *(const bf16x8*)(vbase + (kt + 1) * 64);
            vr1 = *(const bf16x8*)(vbase + (kt + 1) * 64 + 8);
        }

        // S^T = K.Q^T
        const int fsw = (l16 & 7) << 3;  // row&7 == l16&7 for rows f*16+l16
        f32x4 st[4][2];
#pragma unroll
        for (int f = 0; f < 4; ++f) {
            const int krow = (f * 16 + l16) * 64;
            bf16x8 ka0 = *(bf16x8*)&Ks[krow + ((quad * 8) ^ fsw)];
            bf16x8 ka1 = *(bf16x8*)&Ks[krow + ((32 + quad * 8) ^ fsw)];
#pragma unroll
            for (int qg = 0; qg < 2; ++qg) {
                f32x4 c = {0.f, 0.f, 0.f, 0.f};
                c = __builtin_amdgcn_mfma_f32_16x16x32_bf16(ka0, qb[qg][0], c, 0, 0, 0);
                c = __builtin_amdgcn_mfma_f32_16x16x32_bf16(ka1, qb[qg][1], c, 0, 0, 0);
                st[f][qg] = c;
            }
        }

        if (!fastmask) {
#pragma unroll
            for (int f = 0; f < 4; ++f) {
                const float4 mk4 = *(const float4*)&Ms[kt * 64 + f * 16 + quad * 4];
                const float mkk[4] = {mk4.x, mk4.y, mk4.z, mk4.w};
#pragma unroll
                for (int qg = 0; qg < 2; ++qg)
#pragma unroll
                    for (int r = 0; r < 4; ++r) {
                        const float ext = mq[qg] * mkk[r];
                        // st is in log2 domain: 1e9*log2e = 1.4427e9
                        st[f][qg][r] =
                            ext * st[f][qg][r] - (1.0f - ext) * 1.4426950e9f;
                    }
            }
        }

        // exp2 (no shift), lane-partial sums, pack P into swizzled Ps
#pragma unroll
        for (int qg = 0; qg < 2; ++qg) {
            const int row = w * 32 + qg * 16 + l16;
            const int sw = (row & 7) << 3;
            bf16* prow = &Ps[row * 64];
#pragma unroll
            for (int f = 0; f < 4; ++f) {
                float p0 = __builtin_amdgcn_exp2f(st[f][qg][0]);
                float p1 = __builtin_amdgcn_exp2f(st[f][qg][1]);
                float p2 = __builtin_amdgcn_exp2f(st[f][qg][2]);
                float p3 = __builtin_amdgcn_exp2f(st[f][qg][3]);
                l_i[qg] += (p0 + p1) + (p2 + p3);
                bf16x4 pk = {(bf16)p0, (bf16)p1, (bf16)p2, (bf16)p3};
                *(bf16x4*)&prow[(f * 16 + quad * 4) ^ sw] = pk;
            }
        }

        // O^T += V^T.P^T (Ps rows wave-local: no barrier)
        bf16x8 pb[2][2];
#pragma unroll
        for (int qg = 0; qg < 2; ++qg) {
            const int row = w * 32 + qg * 16 + l16;
            const int sw = (row & 7) << 3;
#pragma unroll
            for (int hf = 0; hf < 2; ++hf)
                pb[qg][hf] =
                    *(bf16x8*)&Ps[row * 64 + ((hf * 32 + quad * 8) ^ sw)];
        }
#pragma unroll
        for (int fd = 0; fd < 4; ++fd) {
            const int vrow = (fd * 16 + l16) * 64;
            bf16x8 va0 = *(bf16x8*)&Vts[vrow + ((quad * 8) ^ fsw)];
            bf16x8 va1 = *(bf16x8*)&Vts[vrow + ((32 + quad * 8) ^ fsw)];
#pragma unroll
            for (int qg = 0; qg < 2; ++qg) {
                f32x4 c = acc[fd][qg];
                c = __builtin_amdgcn_mfma_f32_16x16x32_bf16(va0, pb[qg][0], c, 0, 0, 0);
                c = __builtin_amdgcn_mfma_f32_16x16x32_bf16(va1, pb[qg][1], c, 0, 0, 0);
                acc[fd][qg] = c;
            }
        }
    }

    // final row-sum reduction across quads (query id = l16 only)
#pragma unroll
    for (int qg = 0; qg < 2; ++qg) {
        l_i[qg] += __shfl_xor(l_i[qg], 16);
        l_i[qg] += __shfl_xor(l_i[qg], 32);
    }

    // epilogue: ctx pre-split bf16 hi/lo [B*S][768] (split done ONCE here)
#pragma unroll
    for (int qg = 0; qg < 2; ++qg) {
        const float inv = 1.0f / l_i[qg];
        const size_t row = (size_t)b * SEQ + qt * 128 + w * 32 + qg * 16 + l16;
#pragma unroll
        for (int fd = 0; fd < 4; ++fd) {
            bf16 hi[4], lo[4];
#pragma unroll
            for (int r = 0; r < 4; ++r) {
                const float o = acc[fd][qg][r] * inv;
                hi[r] = (bf16)o;
                lo[r] = (bf16)(o - (float)hi[r]);
            }
            const size_t off = row * HIDDEN + h * 64 + fd * 16 + quad * 4;
            *(bf16x4*)(ctx_hi + off) = *(bf16x4*)&hi[0];
            *(bf16x4*)(ctx_lo + off) = *(bf16x4*)&lo[0];
        }
    }
}

// ---------------------------------------------------------------------------
// Output GEMM — R10 structure (verified best): T3-min 2-phase dbuf at BK=32,
// one barrier per K-step, STAGE before COMPUTE. 64B-row involution both
// sides; XCD swizzle (R9). 3-term: ah*bh + ah*bl + al*bh.
// ---------------------------------------------------------------------------
__global__ __launch_bounds__(256) void gemm_out(const bf16* __restrict__ Ah,
                                                const bf16* __restrict__ Al,
                                                const bf16* __restrict__ Bhi,
                                                const bf16* __restrict__ Blo,
                                                const float* __restrict__ bo,
                                                float* __restrict__ fout) {
    __shared__ bf16 Ash[2][128 * 32];
    __shared__ bf16 Asl[2][128 * 32];
    __shared__ bf16 Bsh[2][64 * 32];
    __shared__ bf16 Bsl[2][64 * 32];

    const int tid = threadIdx.x;
    const int ln = tid & 63, wv = tid >> 6;
    const int quad = ln >> 4, l16 = ln & 15;
    const int wm = wv >> 1, wn = wv & 1;

    // XCD swizzle (bijective, 768%8==0)
    const int wg = blockIdx.x;
    const int xcd = wg & 7, i6 = wg >> 3;  // i6 in 0..95
    const int n0 = (i6 % 12) * 64;
    const int m0 = (xcd * 8 + i6 / 12) * 128;

    f32x4 acc[4][2];
#pragma unroll
    for (int i = 0; i < 4; ++i)
#pragma unroll
        for (int j = 0; j < 2; ++j) acc[i][j] = (f32x4){0.f, 0.f, 0.f, 0.f};

    const int srow = ln >> 2;
    const int bcol_sw = ((ln & 3) << 4) ^ (((ln >> 3) & 3) << 4);
    const char* gAh =
        (const char*)Ah + ((size_t)(m0 + wv * 32 + srow) * HIDDEN) * 2 + bcol_sw;
    const char* gAl =
        (const char*)Al + ((size_t)(m0 + wv * 32 + srow) * HIDDEN) * 2 + bcol_sw;
    const char* gBh =
        (const char*)Bhi + ((size_t)(n0 + wv * 16 + srow) * HIDDEN) * 2 + bcol_sw;
    const char* gBl =
        (const char*)Blo + ((size_t)(n0 + wv * 16 + srow) * HIDDEN) * 2 + bcol_sw;

    const int fsw = ((l16 >> 1) & 3) << 4;  // fragment byte-swizzle

    auto STAGE = [&](int b, int k0) {
#pragma unroll
        for (int j = 0; j < 2; ++j) {  // A hi/lo: wave rows [wv*32,+32)
            load_lds16(gAh + (size_t)k0 * 2 + (size_t)j * (16 * HIDDEN * 2),
                       &Ash[b][(wv * 32 + j * 16) * 32]);
            load_lds16(gAl + (size_t)k0 * 2 + (size_t)j * (16 * HIDDEN * 2),
                       &Asl[b][(wv * 32 + j * 16) * 32]);
        }
        // B hi/lo: wave rows [wv*16,+16)
        load_lds16(gBh + (size_t)k0 * 2, &Bsh[b][(wv * 16) * 32]);
        load_lds16(gBl + (size_t)k0 * 2, &Bsl[b][(wv * 16) * 32]);
    };

    auto COMPUTE = [&](int b) {
        bf16x8 ah[4], al[4], bh[2], bl[2];
#pragma unroll
        for (int i = 0; i < 4; ++i) {
            const int row = (wm * 64 + i * 16 + l16) * 64;
            ah[i] = *(const bf16x8*)((const char*)&Ash[b][0] + row +
                                     ((quad * 16) ^ fsw));
            al[i] = *(const bf16x8*)((const char*)&Asl[b][0] + row +
                                     ((quad * 16) ^ fsw));
        }
#pragma unroll
        for (int i = 0; i < 2; ++i) {
            const int row = (wn * 32 + i * 16 + l16) * 64;
            bh[i] = *(const bf16x8*)((const char*)&Bsh[b][0] + row +
                                     ((quad * 16) ^ fsw));
            bl[i] = *(const bf16x8*)((const char*)&Bsl[b][0] + row +
                                     ((quad * 16) ^ fsw));
        }
#pragma unroll
        for (int mi = 0; mi < 4; ++mi)
#pragma unroll
            for (int ni = 0; ni < 2; ++ni) {
                f32x4 c = acc[mi][ni];
                c = __builtin_amdgcn_mfma_f32_16x16x32_bf16(ah[mi], bh[ni], c, 0, 0, 0);
                c = __builtin_amdgcn_mfma_f32_16x16x32_bf16(ah[mi], bl[ni], c, 0, 0, 0);
                c = __builtin_amdgcn_mfma_f32_16x16x32_bf16(al[mi], bh[ni], c, 0, 0, 0);
                acc[mi][ni] = c;
            }
    };

    STAGE(0, 0);
    __syncthreads();

    for (int step = 0; step < 24; step += 2) {
        if (step + 1 < 24) STAGE(1, (step + 1) * 32);
        COMPUTE(0);
        __syncthreads();
        if (step + 2 < 24) STAGE(0, (step + 2) * 32);
        COMPUTE(1);
        __syncthreads();
    }

#pragma unroll
    for (int ni = 0; ni < 2; ++ni) {
        const int n = n0 + wn * 32 + ni * 16 + l16;
        const float bb = bo[n];
#pragma unroll
        for (int mi = 0; mi < 4; ++mi)
#pragma unroll
            for (int r = 0; r < 4; ++r) {
                const int m = m0 + wm * 64 + mi * 16 + quad * 4 + r;
                float x = acc[mi][ni][r] + bb;
                x = 0.5f * x * (1.0f + erff(x * 0.70710678118654752440f));
                fout[(size_t)m * HIDDEN + n] = x;
            }
    }
}

// ---------------------------------------------------------------------------
extern "C" void kernel_launch(void* const* d_in, const int* in_sizes, int n_in,
                              void* d_out, int out_size, void* d_ws, size_t ws_size,
                              hipStream_t stream) {
    const float* X    = (const float*)d_in[0];
    const float* mask = (const float*)d_in[1];
    const float* Wq   = (const float*)d_in[2];
    const float* bq   = (const float*)d_in[3];
    const float* Wk   = (const float*)d_in[4];
    const float* bk   = (const float*)d_in[5];
    const float* Wv   = (const float*)d_in[6];
    const float* bv   = (const float*)d_in[7];
    const float* Wo   = (const float*)d_in[8];
    const float* bo   = (const float*)d_in[9];
    float* out = (float*)d_out;

    char* w = (char*)d_ws;
    const size_t NE = (size_t)BATCH * SEQ * HIDDEN;  // 6.29M elems
    bf16* q_ws   = (bf16*)w;  w += NE * 2;
    bf16* k_ws   = (bf16*)w;  w += NE * 2;
    bf16* vt_ws  = (bf16*)w;  w += NE * 2;
    bf16* ctx_hi = (bf16*)w;  w += NE * 2;
    bf16* ctx_lo = (bf16*)w;  w += NE * 2;
    bf16* Xb     = (bf16*)w;  w += NE * 2;
    bf16* Wt     = (bf16*)w;  w += (size_t)3 * HIDDEN * HIDDEN * 2;
    bf16* Wot_hi = (bf16*)w;  w += (size_t)HIDDEN * HIDDEN * 2;
    bf16* Wot_lo = (bf16*)w;  w += (size_t)HIDDEN * HIDDEN * 2;

    prep_xw<<<3648, 256, 0, stream>>>(X, Xb, Wq, Wk, Wv, Wo, Wt, Wot_hi,
                                      Wot_lo);
    gemm_qkv<<<dim3(768), 256, 0, stream>>>(Xb, Wt, bq, bk, bv, q_ws, k_ws,
                                            vt_ws);
    attn_mfma<<<dim3(16 * NH * BATCH), 256, 0, stream>>>(
        q_ws, k_ws, vt_ws, mask, ctx_hi, ctx_lo);
    gemm_out<<<dim3(768), 256, 0, stream>>>(ctx_hi, ctx_lo, Wot_hi, Wot_lo,
                                            bo, out);
}